// Round 2
// baseline (35.412 us; speedup 1.0000x reference)
//
#include <hip/hip_runtime.h>

// y[b,q] = sum_{d,f} amp[b,d,f] * sin(x_q[b,q,d] * freq[b,d,f])
//   z  : [B, 2*D*F]  (first D*F = amplitudes, second D*F = freqs), row-major [d][f]
//   x_q: [B, Q, D]
//   out: [B, Q]
//
// Parallelization: 4 threads per q (each owns 16 of the 64 d's), so the grid
// is 2048 blocks x 256 threads = 8192 waves -> up to 8 waves/SIMD to hide
// trans-pipe + LDS latency (R1 was 2 waves/SIMD and latency-bound at 40
// cyc/term vs the 8-cycle trans floor).
#define ND 64
#define NF 16
#define QPB 64  // q's per 256-thread block (4 threads per q)

__global__ __launch_bounds__(256) void sinreg_kernel(
    const float* __restrict__ z,
    const float* __restrict__ xq,
    float* __restrict__ out,
    int B, int Q) {
  __shared__ float s_amp[ND * NF];
  __shared__ float s_frq[ND * NF];

  const int b = blockIdx.y;
  const int tid = threadIdx.x;
  constexpr float INV2PI = 0.15915494309189535f;  // radians -> revolutions for v_sin

  // Stage this b's 8KB of coefficients into LDS (coalesced float4), folding
  // the 1/2pi into freq so the inner loop is mul+fract+sin+fma only.
  {
    const float* zb = z + (size_t)b * (2 * ND * NF);
    const float4* za = reinterpret_cast<const float4*>(zb);            // amplitudes
    const float4* zf = reinterpret_cast<const float4*>(zb + ND * NF);  // freqs
    float4 a = za[tid];
    float4 f = zf[tid];
    reinterpret_cast<float4*>(s_amp)[tid] = a;
    f.x *= INV2PI; f.y *= INV2PI; f.z *= INV2PI; f.w *= INV2PI;
    reinterpret_cast<float4*>(s_frq)[tid] = f;
  }
  __syncthreads();

  const int qloc = tid >> 2;   // 0..63
  const int dq   = tid & 3;    // which 16-d chunk this thread owns
  const int q = blockIdx.x * QPB + qloc;

  // Preload this thread's 16 x-values (compile-time-indexed only; rule #20).
  const float4* xrow =
      reinterpret_cast<const float4*>(xq + ((size_t)b * Q + q) * ND + dq * 16);
  float4 xv0 = xrow[0], xv1 = xrow[1], xv2 = xrow[2], xv3 = xrow[3];

  float acc0 = 0.f, acc1 = 0.f, acc2 = 0.f, acc3 = 0.f;

#define TERM4(XD, DIDX)                                                        \
  {                                                                            \
    const float4* fp = reinterpret_cast<const float4*>(&s_frq[(DIDX) * NF]);   \
    const float4* ap = reinterpret_cast<const float4*>(&s_amp[(DIDX) * NF]);   \
    _Pragma("unroll")                                                          \
    for (int f4 = 0; f4 < 4; ++f4) {                                           \
      float4 fr = fp[f4];                                                      \
      float4 am = ap[f4];                                                      \
      acc0 = fmaf(__builtin_amdgcn_sinf(__builtin_amdgcn_fractf((XD) * fr.x)), \
                  am.x, acc0);                                                 \
      acc1 = fmaf(__builtin_amdgcn_sinf(__builtin_amdgcn_fractf((XD) * fr.y)), \
                  am.y, acc1);                                                 \
      acc2 = fmaf(__builtin_amdgcn_sinf(__builtin_amdgcn_fractf((XD) * fr.z)), \
                  am.z, acc2);                                                 \
      acc3 = fmaf(__builtin_amdgcn_sinf(__builtin_amdgcn_fractf((XD) * fr.w)), \
                  am.w, acc3);                                                 \
    }                                                                          \
  }

  const int d0 = dq * 16;
  TERM4(xv0.x, d0 + 0)  TERM4(xv0.y, d0 + 1)  TERM4(xv0.z, d0 + 2)  TERM4(xv0.w, d0 + 3)
  TERM4(xv1.x, d0 + 4)  TERM4(xv1.y, d0 + 5)  TERM4(xv1.z, d0 + 6)  TERM4(xv1.w, d0 + 7)
  TERM4(xv2.x, d0 + 8)  TERM4(xv2.y, d0 + 9)  TERM4(xv2.z, d0 + 10) TERM4(xv2.w, d0 + 11)
  TERM4(xv3.x, d0 + 12) TERM4(xv3.y, d0 + 13) TERM4(xv3.z, d0 + 14) TERM4(xv3.w, d0 + 15)
#undef TERM4

  float acc = (acc0 + acc1) + (acc2 + acc3);
  // Reduce the 4 partial sums held by lanes 4k..4k+3 (same q).
  acc += __shfl_xor(acc, 1);
  acc += __shfl_xor(acc, 2);
  if (dq == 0) out[(size_t)b * Q + q] = acc;
}

extern "C" void kernel_launch(void* const* d_in, const int* in_sizes, int n_in,
                              void* d_out, int out_size, void* d_ws, size_t ws_size,
                              hipStream_t stream) {
  const float* z  = (const float*)d_in[0];
  const float* xq = (const float*)d_in[1];
  float* out = (float*)d_out;

  const int B = in_sizes[0] / (2 * ND * NF);   // 32
  const int Q = in_sizes[1] / (B * ND);        // 4096

  dim3 grid(Q / QPB, B);
  sinreg_kernel<<<grid, 256, 0, stream>>>(z, xq, out, B, Q);
}

// Round 3
// 26.622 us; speedup vs baseline: 1.3302x; 1.3302x over previous
//
#include <hip/hip_runtime.h>

// y[b,q] = sum_{d,f} amp[b,d,f] * sin(x_q[b,q,d] * freq[b,d,f])
//   z  : [B, 2*D*F]  (amps then freqs, row-major [d][f])
//   x_q: [B, Q, D]
//   out: [B, Q]
//
// Structure (R3): block = 256 threads = 4 waves; each wave handles the SAME
// 64 q's (q = blockIdx.x*64 + lane) but its own 16-d slice (d0 = 16*waveid,
// forced to SGPR via readfirstlane so coefficient addresses are wave-uniform
// -> scalar loads, no LDS/VMEM competing with the v_sin hot loop).
// Grid = 2048 blocks -> 8 waves/SIMD to hide s_load + trans latency.
#define ND 64
#define NF 16

__global__ __launch_bounds__(256, 4) void sinreg_kernel(
    const float* __restrict__ z,
    const float* __restrict__ xq,
    float* __restrict__ out,
    int B, int Q) {
  __shared__ float s_part[4][64];

  const int b = blockIdx.y;
  const int lane = threadIdx.x & 63;
  // wave id, forced uniform (SGPR) so coeff addressing stays scalar
  const int wv = __builtin_amdgcn_readfirstlane((int)(threadIdx.x >> 6));  // 0..3
  const int q = blockIdx.x * 64 + lane;

  const float* __restrict__ zb  = z + (size_t)b * (2 * ND * NF);
  const float* __restrict__ amp = zb + (16 * wv) * NF;            // this wave's amp slice
  const float* __restrict__ frq = zb + ND * NF + (16 * wv) * NF;  // this wave's freq slice

  // This thread's 16 x-values (compile-time-indexed; stays in VGPRs).
  const float4* __restrict__ xrow =
      reinterpret_cast<const float4*>(xq + ((size_t)b * Q + q) * ND + 16 * wv);
  float4 xv0 = xrow[0], xv1 = xrow[1], xv2 = xrow[2], xv3 = xrow[3];

  constexpr float INV2PI = 0.15915494309189535f;  // radians -> revolutions for v_sin
  const float xs[16] = {
      xv0.x * INV2PI, xv0.y * INV2PI, xv0.z * INV2PI, xv0.w * INV2PI,
      xv1.x * INV2PI, xv1.y * INV2PI, xv1.z * INV2PI, xv1.w * INV2PI,
      xv2.x * INV2PI, xv2.y * INV2PI, xv2.z * INV2PI, xv2.w * INV2PI,
      xv3.x * INV2PI, xv3.y * INV2PI, xv3.z * INV2PI, xv3.w * INV2PI};

  float acc0 = 0.f, acc1 = 0.f, acc2 = 0.f, acc3 = 0.f;

  #pragma unroll
  for (int dd = 0; dd < 16; ++dd) {
    const float xsd = xs[dd];
    #pragma unroll
    for (int f = 0; f < NF; f += 4) {
      // coefficient loads are wave-uniform -> s_load (scalar pipe, K$-resident)
      acc0 = fmaf(__builtin_amdgcn_sinf(__builtin_amdgcn_fractf(xsd * frq[dd * NF + f + 0])),
                  amp[dd * NF + f + 0], acc0);
      acc1 = fmaf(__builtin_amdgcn_sinf(__builtin_amdgcn_fractf(xsd * frq[dd * NF + f + 1])),
                  amp[dd * NF + f + 1], acc1);
      acc2 = fmaf(__builtin_amdgcn_sinf(__builtin_amdgcn_fractf(xsd * frq[dd * NF + f + 2])),
                  amp[dd * NF + f + 2], acc2);
      acc3 = fmaf(__builtin_amdgcn_sinf(__builtin_amdgcn_fractf(xsd * frq[dd * NF + f + 3])),
                  amp[dd * NF + f + 3], acc3);
    }
  }

  // Cross-wave reduction: each wave wrote a partial for its 64 q's.
  s_part[wv][lane] = (acc0 + acc1) + (acc2 + acc3);
  __syncthreads();
  if (threadIdx.x < 64) {
    float r = (s_part[0][lane] + s_part[1][lane]) + (s_part[2][lane] + s_part[3][lane]);
    out[(size_t)b * Q + (size_t)blockIdx.x * 64 + lane] = r;
  }
}

extern "C" void kernel_launch(void* const* d_in, const int* in_sizes, int n_in,
                              void* d_out, int out_size, void* d_ws, size_t ws_size,
                              hipStream_t stream) {
  const float* z  = (const float*)d_in[0];
  const float* xq = (const float*)d_in[1];
  float* out = (float*)d_out;

  const int B = in_sizes[0] / (2 * ND * NF);   // 32
  const int Q = in_sizes[1] / (B * ND);        // 4096

  dim3 grid(Q / 64, B);
  sinreg_kernel<<<grid, 256, 0, stream>>>(z, xq, out, B, Q);
}